// Round 1
// baseline (2605.925 us; speedup 1.0000x reference)
//
#include <hip/hip_runtime.h>
#include <math.h>

#define NN 100000
#define EE 3200000
#define ET (EE + NN)
#define NG 64

// workspace layout (float offsets)
#define OFF_XL1   0u
#define OFF_XR1   3200000u
#define OFF_ACC1  6400000u
#define OFF_DEN1  9600000u
#define OFF_H     10400000u
#define OFF_HL2   13600000u
#define OFF_HR2   20000000u
#define OFF_ACC2  26400000u
#define OFF_DEN2  32800000u
#define OFF_POOL  32900000u
#define OFF_CNT   32904096u
#define WS_FLOATS 32904160u

__device__ __forceinline__ float lrelu(float v) { return v > 0.0f ? v : 0.2f * v; }

// -------- layer-1 transform: xl1 = x@W1l + b1l, xr1 = x@W1r + b1r --------
// block 256 threads = 16 nodes x 16 threads; each thread 4 output cols of 64.
__global__ __launch_bounds__(256) void k_xform1(
    const float* __restrict__ x,
    const float* __restrict__ Wl, const float* __restrict__ bl,
    const float* __restrict__ Wr, const float* __restrict__ br,
    float* __restrict__ xl1, float* __restrict__ xr1) {
  __shared__ float Wlds[256 * 64];
  int tid = threadIdx.x;
  for (int i = tid; i < 256 * 64; i += 256) {
    int k = i >> 6, c = i & 63;
    Wlds[i] = (c < 32) ? Wl[k * 32 + c] : Wr[k * 32 + (c - 32)];
  }
  __syncthreads();
  int n = blockIdx.x * 16 + (tid >> 4);
  int cbase = (tid & 15) * 4;
  const float4* xrow = (const float4*)(x + (size_t)n * 256);
  float a0 = 0.f, a1 = 0.f, a2 = 0.f, a3 = 0.f;
#pragma unroll 4
  for (int k = 0; k < 256; k += 4) {
    float4 xv = xrow[k >> 2];
    const float* wr = &Wlds[k * 64 + cbase];
    float4 w0 = *(const float4*)(wr);
    float4 w1 = *(const float4*)(wr + 64);
    float4 w2 = *(const float4*)(wr + 128);
    float4 w3 = *(const float4*)(wr + 192);
    a0 += xv.x * w0.x + xv.y * w1.x + xv.z * w2.x + xv.w * w3.x;
    a1 += xv.x * w0.y + xv.y * w1.y + xv.z * w2.y + xv.w * w3.y;
    a2 += xv.x * w0.z + xv.y * w1.z + xv.z * w2.z + xv.w * w3.z;
    a3 += xv.x * w0.w + xv.y * w1.w + xv.z * w2.w + xv.w * w3.w;
  }
  if (cbase < 32) {
    float4 o = { a0 + bl[cbase], a1 + bl[cbase + 1], a2 + bl[cbase + 2], a3 + bl[cbase + 3] };
    *(float4*)(xl1 + (size_t)n * 32 + cbase) = o;
  } else {
    int c2 = cbase - 32;
    float4 o = { a0 + br[c2], a1 + br[c2 + 1], a2 + br[c2 + 2], a3 + br[c2 + 3] };
    *(float4*)(xr1 + (size_t)n * 32 + c2) = o;
  }
}

// -------- layer-1 edge pass: 8 lanes per edge, lane = head --------
__global__ __launch_bounds__(256) void k_edge1(
    const int* __restrict__ ei,
    const float* __restrict__ xl1, const float* __restrict__ xr1,
    const float* __restrict__ att,
    float* __restrict__ acc1, float* __restrict__ den1) {
  int gtid = blockIdx.x * 256 + threadIdx.x;
  int lane8 = gtid & 7;
  int estart = gtid >> 3;
  int estride = (gridDim.x * 256) >> 3;
  float4 av = *(const float4*)(att + lane8 * 4);
  for (int e = estart; e < ET; e += estride) {
    int s, d;
    if (e < EE) { s = ei[e]; d = ei[EE + e]; }
    else { s = e - EE; d = s; }
    float4 xv = *(const float4*)(xl1 + (size_t)s * 32 + lane8 * 4);
    float4 rv = *(const float4*)(xr1 + (size_t)d * 32 + lane8 * 4);
    float m0 = lrelu(xv.x + rv.x);
    float m1 = lrelu(xv.y + rv.y);
    float m2 = lrelu(xv.z + rv.z);
    float m3 = lrelu(xv.w + rv.w);
    float a = m0 * av.x + m1 * av.y + m2 * av.z + m3 * av.w;
    float w = __expf(a);
    atomicAdd(den1 + (size_t)d * 8 + lane8, w);
    float* ap = acc1 + (size_t)d * 32 + lane8 * 4;
    atomicAdd(ap + 0, w * xv.x);
    atomicAdd(ap + 1, w * xv.y);
    atomicAdd(ap + 2, w * xv.z);
    atomicAdd(ap + 3, w * xv.w);
  }
}

// -------- layer-1 node: h = ELU(acc/den + bias1) --------
__global__ __launch_bounds__(256) void k_node1(
    const float* __restrict__ acc1, const float* __restrict__ den1,
    const float* __restrict__ bias1, float* __restrict__ h) {
  int total = NN * 32;
  for (int idx = blockIdx.x * 256 + threadIdx.x; idx < total; idx += gridDim.x * 256) {
    int n = idx >> 5, c = idx & 31;
    float v = acc1[idx] / (den1[(size_t)n * 8 + (c >> 2)] + 1e-16f) + bias1[c];
    h[idx] = v > 0.0f ? v : expm1f(v);
  }
}

// -------- layer-2 transform: hl2 = h@W2l + b2l, hr2 = h@W2r + b2r --------
// block 256 = 8 nodes x 32 threads; each thread 4 cols of 128.
__global__ __launch_bounds__(256) void k_xform2(
    const float* __restrict__ h,
    const float* __restrict__ Wl, const float* __restrict__ bl,
    const float* __restrict__ Wr, const float* __restrict__ br,
    float* __restrict__ hl2, float* __restrict__ hr2) {
  __shared__ float Wlds[32 * 128];
  int tid = threadIdx.x;
  for (int i = tid; i < 32 * 128; i += 256) {
    int k = i >> 7, c = i & 127;
    Wlds[i] = (c < 64) ? Wl[k * 64 + c] : Wr[k * 64 + (c - 64)];
  }
  __syncthreads();
  int n = blockIdx.x * 8 + (tid >> 5);
  int cbase = (tid & 31) * 4;
  const float4* hrow = (const float4*)(h + (size_t)n * 32);
  float a0 = 0.f, a1 = 0.f, a2 = 0.f, a3 = 0.f;
#pragma unroll
  for (int k = 0; k < 32; k += 4) {
    float4 xv = hrow[k >> 2];
    const float* wr = &Wlds[k * 128 + cbase];
    float4 w0 = *(const float4*)(wr);
    float4 w1 = *(const float4*)(wr + 128);
    float4 w2 = *(const float4*)(wr + 256);
    float4 w3 = *(const float4*)(wr + 384);
    a0 += xv.x * w0.x + xv.y * w1.x + xv.z * w2.x + xv.w * w3.x;
    a1 += xv.x * w0.y + xv.y * w1.y + xv.z * w2.y + xv.w * w3.y;
    a2 += xv.x * w0.z + xv.y * w1.z + xv.z * w2.z + xv.w * w3.z;
    a3 += xv.x * w0.w + xv.y * w1.w + xv.z * w2.w + xv.w * w3.w;
  }
  if (cbase < 64) {
    float4 o = { a0 + bl[cbase], a1 + bl[cbase + 1], a2 + bl[cbase + 2], a3 + bl[cbase + 3] };
    *(float4*)(hl2 + (size_t)n * 64 + cbase) = o;
  } else {
    int c2 = cbase - 64;
    float4 o = { a0 + br[c2], a1 + br[c2 + 1], a2 + br[c2 + 2], a3 + br[c2 + 3] };
    *(float4*)(hr2 + (size_t)n * 64 + c2) = o;
  }
}

// -------- layer-2 edge pass: one wave (64 lanes) per edge --------
__global__ __launch_bounds__(256) void k_edge2(
    const int* __restrict__ ei,
    const float* __restrict__ hl2, const float* __restrict__ hr2,
    const float* __restrict__ att2,
    float* __restrict__ acc2, float* __restrict__ den2) {
  int lane = threadIdx.x & 63;
  int wid = (blockIdx.x * 256 + threadIdx.x) >> 6;
  int wstride = (gridDim.x * 256) >> 6;
  float ac = att2[lane];
  for (int e = wid; e < ET; e += wstride) {
    int s, d;
    if (e < EE) { s = ei[e]; d = ei[EE + e]; }
    else { s = e - EE; d = s; }
    float hl = hl2[(size_t)s * 64 + lane];
    float hr = hr2[(size_t)d * 64 + lane];
    float m = lrelu(hl + hr);
    float p = m * ac;
#pragma unroll
    for (int off = 32; off; off >>= 1) p += __shfl_xor(p, off);
    float w = __expf(p);
    atomicAdd(acc2 + (size_t)d * 64 + lane, w * hl);
    if (lane == 0) atomicAdd(den2 + d, w);
  }
}

// -------- layer-2 node + global mean pool accumulation --------
__global__ __launch_bounds__(256) void k_node2pool(
    const float* __restrict__ acc2, const float* __restrict__ den2,
    const float* __restrict__ bias2, const int* __restrict__ batch,
    float* __restrict__ pool, float* __restrict__ cnt) {
  __shared__ float ssum[NG * 64];
  __shared__ float scnt[NG];
  int tid = threadIdx.x;
  for (int i = tid; i < NG * 64; i += 256) ssum[i] = 0.0f;
  if (tid < NG) scnt[tid] = 0.0f;
  __syncthreads();
  int total = NN * 64;
  for (int idx = blockIdx.x * 256 + tid; idx < total; idx += gridDim.x * 256) {
    int n = idx >> 6, c = idx & 63;
    int g = batch[n];
    float v = acc2[idx] / (den2[n] + 1e-16f) + bias2[c];
    atomicAdd(&ssum[g * 64 + c], v);
    if (c == 0) atomicAdd(&scnt[g], 1.0f);
  }
  __syncthreads();
  for (int i = tid; i < NG * 64; i += 256) atomicAdd(pool + i, ssum[i]);
  if (tid < NG) atomicAdd(cnt + tid, scnt[tid]);
}

__global__ __launch_bounds__(256) void k_final(
    const float* __restrict__ pool, const float* __restrict__ cnt,
    float* __restrict__ out) {
  int i = blockIdx.x * 256 + threadIdx.x;
  if (i < NG * 64) out[i] = pool[i] / fmaxf(cnt[i >> 6], 1.0f);
}

extern "C" void kernel_launch(void* const* d_in, const int* in_sizes, int n_in,
                              void* d_out, int out_size, void* d_ws, size_t ws_size,
                              hipStream_t stream) {
  const float* x     = (const float*)d_in[0];
  const int*   ei    = (const int*)d_in[1];
  const int*   batch = (const int*)d_in[2];
  const float* W1l   = (const float*)d_in[3];
  const float* b1l   = (const float*)d_in[4];
  const float* W1r   = (const float*)d_in[5];
  const float* b1r   = (const float*)d_in[6];
  const float* att1  = (const float*)d_in[7];
  const float* bias1 = (const float*)d_in[8];
  const float* W2l   = (const float*)d_in[9];
  const float* b2l   = (const float*)d_in[10];
  const float* W2r   = (const float*)d_in[11];
  const float* b2r   = (const float*)d_in[12];
  const float* att2  = (const float*)d_in[13];
  const float* bias2 = (const float*)d_in[14];
  float* ws = (float*)d_ws;
  float* out = (float*)d_out;

  // zero accumulators (acc1+den1 contiguous, acc2+den2+pool+cnt contiguous)
  hipMemsetAsync(ws + OFF_ACC1, 0, (size_t)(OFF_H - OFF_ACC1) * 4, stream);
  hipMemsetAsync(ws + OFF_ACC2, 0, (size_t)(WS_FLOATS - OFF_ACC2) * 4, stream);

  k_xform1<<<NN / 16, 256, 0, stream>>>(x, W1l, b1l, W1r, b1r, ws + OFF_XL1, ws + OFF_XR1);
  k_edge1<<<4096, 256, 0, stream>>>(ei, ws + OFF_XL1, ws + OFF_XR1, att1,
                                    ws + OFF_ACC1, ws + OFF_DEN1);
  k_node1<<<2048, 256, 0, stream>>>(ws + OFF_ACC1, ws + OFF_DEN1, bias1, ws + OFF_H);
  k_xform2<<<NN / 8, 256, 0, stream>>>(ws + OFF_H, W2l, b2l, W2r, b2r,
                                       ws + OFF_HL2, ws + OFF_HR2);
  k_edge2<<<4096, 256, 0, stream>>>(ei, ws + OFF_HL2, ws + OFF_HR2, att2,
                                    ws + OFF_ACC2, ws + OFF_DEN2);
  k_node2pool<<<1024, 256, 0, stream>>>(ws + OFF_ACC2, ws + OFF_DEN2, bias2, batch,
                                        ws + OFF_POOL, ws + OFF_CNT);
  k_final<<<16, 256, 0, stream>>>(ws + OFF_POOL, ws + OFF_CNT, out);
}

// Round 2
// 1115.384 us; speedup vs baseline: 2.3363x; 2.3363x over previous
//
#include <hip/hip_runtime.h>
#include <math.h>

#define NN 100000
#define EE 3200000
#define ET (EE + NN)
#define NG 64
#define NBLK 391   // ceil(NN/256)

// workspace layout (4-byte units)
#define OFF_XL1   0u
#define OFF_XR1   3200000u
#define OFF_H     6400000u
#define OFF_HL2   9600000u
#define OFF_HR2   16000000u
#define OFF_POOL  22400000u
#define OFF_CNTG  22404096u
#define OFF_DEG   22404160u
#define OFF_RP    22504160u
#define OFF_CUR   22604160u
#define OFF_PART  22704160u
#define OFF_TMP   22704672u
#define OFF_ESRC  22804768u
#define WS_UNITS  26104768u

__device__ __forceinline__ float lrelu(float v) { return v > 0.0f ? v : 0.2f * v; }

// ======================= CSR build =======================
__global__ __launch_bounds__(256) void k_count(const int* __restrict__ ei, int* __restrict__ deg) {
  for (int e = blockIdx.x * 256 + threadIdx.x; e < ET; e += gridDim.x * 256) {
    int d = (e < EE) ? ei[EE + e] : (e - EE);
    atomicAdd(deg + d, 1);
  }
}

__global__ __launch_bounds__(256) void k_scan1(const int* __restrict__ deg,
                                               int* __restrict__ tmp, int* __restrict__ part) {
  __shared__ int sd[256];
  int t = threadIdx.x, b = blockIdx.x, i = b * 256 + t;
  int v = (i < NN) ? deg[i] : 0;
  sd[t] = v;
  __syncthreads();
  for (int o = 1; o < 256; o <<= 1) {
    int u = (t >= o) ? sd[t - o] : 0;
    __syncthreads();
    sd[t] += u;
    __syncthreads();
  }
  tmp[i] = sd[t];
  if (t == 255) part[b] = sd[t];
}

__global__ __launch_bounds__(512) void k_scan2(int* __restrict__ part) {
  __shared__ int sd[512];
  int t = threadIdx.x;
  int v = (t < NBLK) ? part[t] : 0;
  sd[t] = v;
  __syncthreads();
  for (int o = 1; o < 512; o <<= 1) {
    int u = (t >= o) ? sd[t - o] : 0;
    __syncthreads();
    sd[t] += u;
    __syncthreads();
  }
  if (t < NBLK) part[t] = sd[t];
}

__global__ __launch_bounds__(256) void k_scan3(const int* __restrict__ deg,
                                               const int* __restrict__ tmp,
                                               const int* __restrict__ part,
                                               int* __restrict__ rp, int* __restrict__ cur) {
  int b = blockIdx.x, t = threadIdx.x, i = b * 256 + t;
  if (i >= NN) return;
  int excl = tmp[i] - deg[i] + (b > 0 ? part[b - 1] : 0);
  rp[i] = excl;
  cur[i] = excl;
}

__global__ __launch_bounds__(256) void k_scatter(const int* __restrict__ ei,
                                                 int* __restrict__ cur, int* __restrict__ esrc) {
  for (int e = blockIdx.x * 256 + threadIdx.x; e < ET; e += gridDim.x * 256) {
    int s, d;
    if (e < EE) { s = ei[e]; d = ei[EE + e]; }
    else { s = e - EE; d = s; }
    int p = atomicAdd(cur + d, 1);
    esrc[p] = s;
  }
}

// ======================= layer-1 transform =======================
// block 256 = 16 nodes x 16 threads; each thread 4 output cols of 64 (32 l, 32 r).
__global__ __launch_bounds__(256) void k_xform1(
    const float* __restrict__ x,
    const float* __restrict__ Wl, const float* __restrict__ bl,
    const float* __restrict__ Wr, const float* __restrict__ br,
    float* __restrict__ xl1, float* __restrict__ xr1) {
  __shared__ float Wlds[256 * 64];
  int tid = threadIdx.x;
  for (int i = tid; i < 256 * 64; i += 256) {
    int k = i >> 6, c = i & 63;
    Wlds[i] = (c < 32) ? Wl[k * 32 + c] : Wr[k * 32 + (c - 32)];
  }
  __syncthreads();
  int n = blockIdx.x * 16 + (tid >> 4);
  int cbase = (tid & 15) * 4;
  const float4* xrow = (const float4*)(x + (size_t)n * 256);
  float a0 = 0.f, a1 = 0.f, a2 = 0.f, a3 = 0.f;
#pragma unroll 4
  for (int k = 0; k < 256; k += 4) {
    float4 xv = xrow[k >> 2];
    const float* wr = &Wlds[k * 64 + cbase];
    float4 w0 = *(const float4*)(wr);
    float4 w1 = *(const float4*)(wr + 64);
    float4 w2 = *(const float4*)(wr + 128);
    float4 w3 = *(const float4*)(wr + 192);
    a0 += xv.x * w0.x + xv.y * w1.x + xv.z * w2.x + xv.w * w3.x;
    a1 += xv.x * w0.y + xv.y * w1.y + xv.z * w2.y + xv.w * w3.y;
    a2 += xv.x * w0.z + xv.y * w1.z + xv.z * w2.z + xv.w * w3.z;
    a3 += xv.x * w0.w + xv.y * w1.w + xv.z * w2.w + xv.w * w3.w;
  }
  if (cbase < 32) {
    float4 o = { a0 + bl[cbase], a1 + bl[cbase + 1], a2 + bl[cbase + 2], a3 + bl[cbase + 3] };
    *(float4*)(xl1 + (size_t)n * 32 + cbase) = o;
  } else {
    int c2 = cbase - 32;
    float4 o = { a0 + br[c2], a1 + br[c2 + 1], a2 + br[c2 + 2], a3 + br[c2 + 3] };
    *(float4*)(xr1 + (size_t)n * 32 + c2) = o;
  }
}

// ======================= layer-1 gather (fused attention + node) =======================
// 32 lanes per node (lane = h*4+c); 8 nodes per block.
__global__ __launch_bounds__(256) void k_gather1(
    const int* __restrict__ rp, const int* __restrict__ deg, const int* __restrict__ esrc,
    const float* __restrict__ xl1, const float* __restrict__ xr1,
    const float* __restrict__ att1, const float* __restrict__ bias1,
    float* __restrict__ h) {
  int n = blockIdx.x * 8 + (threadIdx.x >> 5);
  if (n >= NN) return;
  int l = threadIdx.x & 31;
  float av = att1[l];
  float xr = xr1[(size_t)n * 32 + l];
  int rpn = rp[n], dg = deg[n];
  float acc = 0.0f, den = 0.0f;
  for (int j = 0; j < dg; ++j) {
    int s = esrc[rpn + j];
    float xl = xl1[(size_t)s * 32 + l];
    float m = lrelu(xl + xr);
    float p = m * av;
    p += __shfl_xor(p, 1);
    p += __shfl_xor(p, 2);
    float w = __expf(p);
    den += w;
    acc += w * xl;
  }
  float v = acc / (den + 1e-16f) + bias1[l];
  h[(size_t)n * 32 + l] = v > 0.0f ? v : expm1f(v);
}

// ======================= layer-2 transform =======================
// block 256 = 8 nodes x 32 threads; each thread 4 cols of 128 (64 l, 64 r).
__global__ __launch_bounds__(256) void k_xform2(
    const float* __restrict__ h,
    const float* __restrict__ Wl, const float* __restrict__ bl,
    const float* __restrict__ Wr, const float* __restrict__ br,
    float* __restrict__ hl2, float* __restrict__ hr2) {
  __shared__ float Wlds[32 * 128];
  int tid = threadIdx.x;
  for (int i = tid; i < 32 * 128; i += 256) {
    int k = i >> 7, c = i & 127;
    Wlds[i] = (c < 64) ? Wl[k * 64 + c] : Wr[k * 64 + (c - 64)];
  }
  __syncthreads();
  int n = blockIdx.x * 8 + (tid >> 5);
  int cbase = (tid & 31) * 4;
  const float4* hrow = (const float4*)(h + (size_t)n * 32);
  float a0 = 0.f, a1 = 0.f, a2 = 0.f, a3 = 0.f;
#pragma unroll
  for (int k = 0; k < 32; k += 4) {
    float4 xv = hrow[k >> 2];
    const float* wr = &Wlds[k * 128 + cbase];
    float4 w0 = *(const float4*)(wr);
    float4 w1 = *(const float4*)(wr + 128);
    float4 w2 = *(const float4*)(wr + 256);
    float4 w3 = *(const float4*)(wr + 384);
    a0 += xv.x * w0.x + xv.y * w1.x + xv.z * w2.x + xv.w * w3.x;
    a1 += xv.x * w0.y + xv.y * w1.y + xv.z * w2.y + xv.w * w3.y;
    a2 += xv.x * w0.z + xv.y * w1.z + xv.z * w2.z + xv.w * w3.z;
    a3 += xv.x * w0.w + xv.y * w1.w + xv.z * w2.w + xv.w * w3.w;
  }
  if (cbase < 64) {
    float4 o = { a0 + bl[cbase], a1 + bl[cbase + 1], a2 + bl[cbase + 2], a3 + bl[cbase + 3] };
    *(float4*)(hl2 + (size_t)n * 64 + cbase) = o;
  } else {
    int c2 = cbase - 64;
    float4 o = { a0 + br[c2], a1 + br[c2 + 1], a2 + br[c2 + 2], a3 + br[c2 + 3] };
    *(float4*)(hr2 + (size_t)n * 64 + c2) = o;
  }
}

// ======================= layer-2 gather + pooling =======================
// 8 lanes per node, each lane 8 channels; contiguous chunk of CH2 nodes per group.
#define CH2 4
__global__ __launch_bounds__(256) void k_gather2(
    const int* __restrict__ rp, const int* __restrict__ deg, const int* __restrict__ esrc,
    const float* __restrict__ hl2, const float* __restrict__ hr2,
    const float* __restrict__ att2, const float* __restrict__ bias2,
    const int* __restrict__ batch,
    float* __restrict__ pool, float* __restrict__ cntg) {
  int gid = (blockIdx.x * 256 + threadIdx.x) >> 3;
  int l8 = threadIdx.x & 7;
  int n0 = gid * CH2;
  if (n0 >= NN) return;
  int n1 = n0 + CH2 < NN ? n0 + CH2 : NN;
  float4 ac0 = *(const float4*)(att2 + l8 * 8);
  float4 ac1 = *(const float4*)(att2 + l8 * 8 + 4);
  float4 bs0 = *(const float4*)(bias2 + l8 * 8);
  float4 bs1 = *(const float4*)(bias2 + l8 * 8 + 4);
  int gcur = batch[n0];
  float4 vs0 = {0,0,0,0}, vs1 = {0,0,0,0};
  float ncnt = 0.0f;
  for (int n = n0; n < n1; ++n) {
    int g = batch[n];
    if (g != gcur) {
      float* pp = pool + (size_t)gcur * 64 + l8 * 8;
      atomicAdd(pp + 0, vs0.x); atomicAdd(pp + 1, vs0.y);
      atomicAdd(pp + 2, vs0.z); atomicAdd(pp + 3, vs0.w);
      atomicAdd(pp + 4, vs1.x); atomicAdd(pp + 5, vs1.y);
      atomicAdd(pp + 6, vs1.z); atomicAdd(pp + 7, vs1.w);
      if (l8 == 0) atomicAdd(cntg + gcur, ncnt);
      vs0 = {0,0,0,0}; vs1 = {0,0,0,0}; ncnt = 0.0f; gcur = g;
    }
    int rpn = rp[n], dg = deg[n];
    const float4* hrp = (const float4*)(hr2 + (size_t)n * 64 + l8 * 8);
    float4 hr0 = hrp[0], hr1 = hrp[1];
    float4 a0 = {0,0,0,0}, a1 = {0,0,0,0};
    float den = 0.0f;
    for (int j = 0; j < dg; ++j) {
      int s = esrc[rpn + j];
      const float4* hp = (const float4*)(hl2 + (size_t)s * 64 + l8 * 8);
      float4 hl0 = hp[0], hl1 = hp[1];
      float p = lrelu(hl0.x + hr0.x) * ac0.x + lrelu(hl0.y + hr0.y) * ac0.y
              + lrelu(hl0.z + hr0.z) * ac0.z + lrelu(hl0.w + hr0.w) * ac0.w
              + lrelu(hl1.x + hr1.x) * ac1.x + lrelu(hl1.y + hr1.y) * ac1.y
              + lrelu(hl1.z + hr1.z) * ac1.z + lrelu(hl1.w + hr1.w) * ac1.w;
      p += __shfl_xor(p, 1);
      p += __shfl_xor(p, 2);
      p += __shfl_xor(p, 4);
      float w = __expf(p);
      den += w;
      a0.x += w * hl0.x; a0.y += w * hl0.y; a0.z += w * hl0.z; a0.w += w * hl0.w;
      a1.x += w * hl1.x; a1.y += w * hl1.y; a1.z += w * hl1.z; a1.w += w * hl1.w;
    }
    float inv = 1.0f / (den + 1e-16f);
    vs0.x += a0.x * inv + bs0.x; vs0.y += a0.y * inv + bs0.y;
    vs0.z += a0.z * inv + bs0.z; vs0.w += a0.w * inv + bs0.w;
    vs1.x += a1.x * inv + bs1.x; vs1.y += a1.y * inv + bs1.y;
    vs1.z += a1.z * inv + bs1.z; vs1.w += a1.w * inv + bs1.w;
    ncnt += 1.0f;
  }
  float* pp = pool + (size_t)gcur * 64 + l8 * 8;
  atomicAdd(pp + 0, vs0.x); atomicAdd(pp + 1, vs0.y);
  atomicAdd(pp + 2, vs0.z); atomicAdd(pp + 3, vs0.w);
  atomicAdd(pp + 4, vs1.x); atomicAdd(pp + 5, vs1.y);
  atomicAdd(pp + 6, vs1.z); atomicAdd(pp + 7, vs1.w);
  if (l8 == 0) atomicAdd(cntg + gcur, ncnt);
}

__global__ __launch_bounds__(256) void k_final(
    const float* __restrict__ pool, const float* __restrict__ cntg,
    float* __restrict__ out) {
  int i = blockIdx.x * 256 + threadIdx.x;
  if (i < NG * 64) out[i] = pool[i] / fmaxf(cntg[i >> 6], 1.0f);
}

extern "C" void kernel_launch(void* const* d_in, const int* in_sizes, int n_in,
                              void* d_out, int out_size, void* d_ws, size_t ws_size,
                              hipStream_t stream) {
  const float* x     = (const float*)d_in[0];
  const int*   ei    = (const int*)d_in[1];
  const int*   batch = (const int*)d_in[2];
  const float* W1l   = (const float*)d_in[3];
  const float* b1l   = (const float*)d_in[4];
  const float* W1r   = (const float*)d_in[5];
  const float* b1r   = (const float*)d_in[6];
  const float* att1  = (const float*)d_in[7];
  const float* bias1 = (const float*)d_in[8];
  const float* W2l   = (const float*)d_in[9];
  const float* b2l   = (const float*)d_in[10];
  const float* W2r   = (const float*)d_in[11];
  const float* b2r   = (const float*)d_in[12];
  const float* att2  = (const float*)d_in[13];
  const float* bias2 = (const float*)d_in[14];
  float* ws = (float*)d_ws;
  int*   wi = (int*)d_ws;
  float* out = (float*)d_out;

  // zero: deg counters + pool/cntg
  hipMemsetAsync(wi + OFF_DEG, 0, (size_t)NN * 4, stream);
  hipMemsetAsync(ws + OFF_POOL, 0, (size_t)(NG * 64 + NG) * 4, stream);

  // CSR build (shared by both layers)
  k_count<<<2048, 256, 0, stream>>>(ei, wi + OFF_DEG);
  k_scan1<<<NBLK, 256, 0, stream>>>(wi + OFF_DEG, wi + OFF_TMP, wi + OFF_PART);
  k_scan2<<<1, 512, 0, stream>>>(wi + OFF_PART);
  k_scan3<<<NBLK, 256, 0, stream>>>(wi + OFF_DEG, wi + OFF_TMP, wi + OFF_PART,
                                    wi + OFF_RP, wi + OFF_CUR);
  k_scatter<<<2048, 256, 0, stream>>>(ei, wi + OFF_CUR, wi + OFF_ESRC);

  // layer 1
  k_xform1<<<NN / 16, 256, 0, stream>>>(x, W1l, b1l, W1r, b1r, ws + OFF_XL1, ws + OFF_XR1);
  k_gather1<<<NN / 8, 256, 0, stream>>>(wi + OFF_RP, wi + OFF_DEG, wi + OFF_ESRC,
                                        ws + OFF_XL1, ws + OFF_XR1, att1, bias1, ws + OFF_H);
  // layer 2
  k_xform2<<<NN / 8, 256, 0, stream>>>(ws + OFF_H, W2l, b2l, W2r, b2r,
                                       ws + OFF_HL2, ws + OFF_HR2);
  k_gather2<<<1024, 256, 0, stream>>>(wi + OFF_RP, wi + OFF_DEG, wi + OFF_ESRC,
                                      ws + OFF_HL2, ws + OFF_HR2, att2, bias2, batch,
                                      ws + OFF_POOL, ws + OFF_CNTG);
  k_final<<<16, 256, 0, stream>>>(ws + OFF_POOL, ws + OFF_CNTG, out);
}

// Round 3
// 877.621 us; speedup vs baseline: 2.9693x; 1.2709x over previous
//
#include <hip/hip_runtime.h>
#include <math.h>

#define NN 100000
#define EE 3200000
#define ET (EE + NN)
#define NG 64
#define NBLK 391   // ceil(NN/256)
#define NPB 128    // pool partial blocks

// workspace layout (4-byte units)
#define OFF_XL1   0u
#define OFF_XR1   3200000u
#define OFF_H     6400000u
#define OFF_HL2   9600000u
#define OFF_HR2   16000000u
#define OFF_OUT2  0u           /* reuses XL1/XR1 (dead after layer 1) */
#define OFF_PPART 22400000u    /* NPB * 4160 */
#define OFF_DEG   22932480u
#define OFF_RP    23032480u
#define OFF_CUR   23132480u
#define OFF_PART  23232480u
#define OFF_TMP   23232992u
#define OFF_ESRC  23333088u
#define WS_UNITS  26633088u

__device__ __forceinline__ float lrelu(float v) { return v > 0.0f ? v : 0.2f * v; }

// ======================= CSR build =======================
__global__ __launch_bounds__(256) void k_count(const int* __restrict__ ei, int* __restrict__ deg) {
  for (int e = blockIdx.x * 256 + threadIdx.x; e < ET; e += gridDim.x * 256) {
    int d = (e < EE) ? ei[EE + e] : (e - EE);
    atomicAdd(deg + d, 1);
  }
}

__global__ __launch_bounds__(256) void k_scan1(const int* __restrict__ deg,
                                               int* __restrict__ tmp, int* __restrict__ part) {
  __shared__ int sd[256];
  int t = threadIdx.x, b = blockIdx.x, i = b * 256 + t;
  int v = (i < NN) ? deg[i] : 0;
  sd[t] = v;
  __syncthreads();
  for (int o = 1; o < 256; o <<= 1) {
    int u = (t >= o) ? sd[t - o] : 0;
    __syncthreads();
    sd[t] += u;
    __syncthreads();
  }
  tmp[i] = sd[t];
  if (t == 255) part[b] = sd[t];
}

__global__ __launch_bounds__(512) void k_scan2(int* __restrict__ part) {
  __shared__ int sd[512];
  int t = threadIdx.x;
  int v = (t < NBLK) ? part[t] : 0;
  sd[t] = v;
  __syncthreads();
  for (int o = 1; o < 512; o <<= 1) {
    int u = (t >= o) ? sd[t - o] : 0;
    __syncthreads();
    sd[t] += u;
    __syncthreads();
  }
  if (t < NBLK) part[t] = sd[t];
}

__global__ __launch_bounds__(256) void k_scan3(const int* __restrict__ deg,
                                               const int* __restrict__ tmp,
                                               const int* __restrict__ part,
                                               int* __restrict__ rp, int* __restrict__ cur) {
  int b = blockIdx.x, t = threadIdx.x, i = b * 256 + t;
  if (i >= NN) return;
  int excl = tmp[i] - deg[i] + (b > 0 ? part[b - 1] : 0);
  rp[i] = excl;
  cur[i] = excl;
}

__global__ __launch_bounds__(256) void k_scatter(const int* __restrict__ ei,
                                                 int* __restrict__ cur, int* __restrict__ esrc) {
  for (int e = blockIdx.x * 256 + threadIdx.x; e < ET; e += gridDim.x * 256) {
    int s, d;
    if (e < EE) { s = ei[e]; d = ei[EE + e]; }
    else { s = e - EE; d = s; }
    int p = atomicAdd(cur + d, 1);
    esrc[p] = s;
  }
}

// ======================= layer-1 transform =======================
__global__ __launch_bounds__(256) void k_xform1(
    const float* __restrict__ x,
    const float* __restrict__ Wl, const float* __restrict__ bl,
    const float* __restrict__ Wr, const float* __restrict__ br,
    float* __restrict__ xl1, float* __restrict__ xr1) {
  __shared__ float Wlds[256 * 64];
  int tid = threadIdx.x;
  for (int i = tid; i < 256 * 64; i += 256) {
    int k = i >> 6, c = i & 63;
    Wlds[i] = (c < 32) ? Wl[k * 32 + c] : Wr[k * 32 + (c - 32)];
  }
  __syncthreads();
  int n = blockIdx.x * 16 + (tid >> 4);
  int cbase = (tid & 15) * 4;
  const float4* xrow = (const float4*)(x + (size_t)n * 256);
  float a0 = 0.f, a1 = 0.f, a2 = 0.f, a3 = 0.f;
#pragma unroll 4
  for (int k = 0; k < 256; k += 4) {
    float4 xv = xrow[k >> 2];
    const float* wr = &Wlds[k * 64 + cbase];
    float4 w0 = *(const float4*)(wr);
    float4 w1 = *(const float4*)(wr + 64);
    float4 w2 = *(const float4*)(wr + 128);
    float4 w3 = *(const float4*)(wr + 192);
    a0 += xv.x * w0.x + xv.y * w1.x + xv.z * w2.x + xv.w * w3.x;
    a1 += xv.x * w0.y + xv.y * w1.y + xv.z * w2.y + xv.w * w3.y;
    a2 += xv.x * w0.z + xv.y * w1.z + xv.z * w2.z + xv.w * w3.z;
    a3 += xv.x * w0.w + xv.y * w1.w + xv.z * w2.w + xv.w * w3.w;
  }
  if (cbase < 32) {
    float4 o = { a0 + bl[cbase], a1 + bl[cbase + 1], a2 + bl[cbase + 2], a3 + bl[cbase + 3] };
    *(float4*)(xl1 + (size_t)n * 32 + cbase) = o;
  } else {
    int c2 = cbase - 32;
    float4 o = { a0 + br[c2], a1 + br[c2 + 1], a2 + br[c2 + 2], a3 + br[c2 + 3] };
    *(float4*)(xr1 + (size_t)n * 32 + c2) = o;
  }
}

// ======================= layer-1 gather, unroll x4 =======================
// 32 lanes per node (lane = h*4+c); 8 nodes per block.
__global__ __launch_bounds__(256) void k_gather1(
    const int* __restrict__ rp, const int* __restrict__ deg, const int* __restrict__ esrc,
    const float* __restrict__ xl1, const float* __restrict__ xr1,
    const float* __restrict__ att1, const float* __restrict__ bias1,
    float* __restrict__ h) {
  int n = blockIdx.x * 8 + (threadIdx.x >> 5);
  if (n >= NN) return;
  int l = threadIdx.x & 31;
  float av = att1[l];
  float xr = xr1[(size_t)n * 32 + l];
  int rpn = rp[n], dg = deg[n];
  float acc = 0.0f, den = 0.0f;
  int j = 0;
  for (; j + 4 <= dg; j += 4) {
    int s0 = esrc[rpn + j + 0];
    int s1 = esrc[rpn + j + 1];
    int s2 = esrc[rpn + j + 2];
    int s3 = esrc[rpn + j + 3];
    float x0 = xl1[(size_t)s0 * 32 + l];
    float x1 = xl1[(size_t)s1 * 32 + l];
    float x2 = xl1[(size_t)s2 * 32 + l];
    float x3 = xl1[(size_t)s3 * 32 + l];
    float p0 = lrelu(x0 + xr) * av;
    float p1 = lrelu(x1 + xr) * av;
    float p2 = lrelu(x2 + xr) * av;
    float p3 = lrelu(x3 + xr) * av;
    p0 += __shfl_xor(p0, 1); p1 += __shfl_xor(p1, 1);
    p2 += __shfl_xor(p2, 1); p3 += __shfl_xor(p3, 1);
    p0 += __shfl_xor(p0, 2); p1 += __shfl_xor(p1, 2);
    p2 += __shfl_xor(p2, 2); p3 += __shfl_xor(p3, 2);
    float w0 = __expf(p0), w1 = __expf(p1), w2 = __expf(p2), w3 = __expf(p3);
    den += w0 + w1 + w2 + w3;
    acc += w0 * x0 + w1 * x1 + w2 * x2 + w3 * x3;
  }
  for (; j < dg; ++j) {
    int s = esrc[rpn + j];
    float xl = xl1[(size_t)s * 32 + l];
    float p = lrelu(xl + xr) * av;
    p += __shfl_xor(p, 1);
    p += __shfl_xor(p, 2);
    float w = __expf(p);
    den += w;
    acc += w * xl;
  }
  float v = acc / (den + 1e-16f) + bias1[l];
  h[(size_t)n * 32 + l] = v > 0.0f ? v : expm1f(v);
}

// ======================= layer-2 transform =======================
__global__ __launch_bounds__(256) void k_xform2(
    const float* __restrict__ h,
    const float* __restrict__ Wl, const float* __restrict__ bl,
    const float* __restrict__ Wr, const float* __restrict__ br,
    float* __restrict__ hl2, float* __restrict__ hr2) {
  __shared__ float Wlds[32 * 128];
  int tid = threadIdx.x;
  for (int i = tid; i < 32 * 128; i += 256) {
    int k = i >> 7, c = i & 127;
    Wlds[i] = (c < 64) ? Wl[k * 64 + c] : Wr[k * 64 + (c - 64)];
  }
  __syncthreads();
  int n = blockIdx.x * 8 + (tid >> 5);
  int cbase = (tid & 31) * 4;
  const float4* hrow = (const float4*)(h + (size_t)n * 32);
  float a0 = 0.f, a1 = 0.f, a2 = 0.f, a3 = 0.f;
#pragma unroll
  for (int k = 0; k < 32; k += 4) {
    float4 xv = hrow[k >> 2];
    const float* wr = &Wlds[k * 128 + cbase];
    float4 w0 = *(const float4*)(wr);
    float4 w1 = *(const float4*)(wr + 128);
    float4 w2 = *(const float4*)(wr + 256);
    float4 w3 = *(const float4*)(wr + 384);
    a0 += xv.x * w0.x + xv.y * w1.x + xv.z * w2.x + xv.w * w3.x;
    a1 += xv.x * w0.y + xv.y * w1.y + xv.z * w2.y + xv.w * w3.y;
    a2 += xv.x * w0.z + xv.y * w1.z + xv.z * w2.z + xv.w * w3.z;
    a3 += xv.x * w0.w + xv.y * w1.w + xv.z * w2.w + xv.w * w3.w;
  }
  if (cbase < 64) {
    float4 o = { a0 + bl[cbase], a1 + bl[cbase + 1], a2 + bl[cbase + 2], a3 + bl[cbase + 3] };
    *(float4*)(hl2 + (size_t)n * 64 + cbase) = o;
  } else {
    int c2 = cbase - 64;
    float4 o = { a0 + br[c2], a1 + br[c2 + 1], a2 + br[c2 + 2], a3 + br[c2 + 3] };
    *(float4*)(hr2 + (size_t)n * 64 + c2) = o;
  }
}

// ======================= layer-2 gather (dense out), unroll x2 =======================
// 8 lanes per node, each lane 8 channels; one node per group, grid covers NN exactly.
__global__ __launch_bounds__(256) void k_gather2(
    const int* __restrict__ rp, const int* __restrict__ deg, const int* __restrict__ esrc,
    const float* __restrict__ hl2, const float* __restrict__ hr2,
    const float* __restrict__ att2, const float* __restrict__ bias2,
    float* __restrict__ out2) {
  int n = (blockIdx.x * 256 + threadIdx.x) >> 3;
  if (n >= NN) return;
  int l8 = threadIdx.x & 7;
  float4 ac0 = *(const float4*)(att2 + l8 * 8);
  float4 ac1 = *(const float4*)(att2 + l8 * 8 + 4);
  float4 bs0 = *(const float4*)(bias2 + l8 * 8);
  float4 bs1 = *(const float4*)(bias2 + l8 * 8 + 4);
  const float4* hrp = (const float4*)(hr2 + (size_t)n * 64 + l8 * 8);
  float4 hr0 = hrp[0], hr1 = hrp[1];
  int rpn = rp[n], dg = deg[n];
  float4 a0 = {0,0,0,0}, a1 = {0,0,0,0};
  float den = 0.0f;
  int j = 0;
  for (; j + 2 <= dg; j += 2) {
    int s0 = esrc[rpn + j];
    int s1 = esrc[rpn + j + 1];
    const float4* hp0 = (const float4*)(hl2 + (size_t)s0 * 64 + l8 * 8);
    const float4* hp1 = (const float4*)(hl2 + (size_t)s1 * 64 + l8 * 8);
    float4 u0 = hp0[0], u1 = hp0[1];
    float4 v0 = hp1[0], v1 = hp1[1];
    float p0 = lrelu(u0.x + hr0.x) * ac0.x + lrelu(u0.y + hr0.y) * ac0.y
             + lrelu(u0.z + hr0.z) * ac0.z + lrelu(u0.w + hr0.w) * ac0.w
             + lrelu(u1.x + hr1.x) * ac1.x + lrelu(u1.y + hr1.y) * ac1.y
             + lrelu(u1.z + hr1.z) * ac1.z + lrelu(u1.w + hr1.w) * ac1.w;
    float p1 = lrelu(v0.x + hr0.x) * ac0.x + lrelu(v0.y + hr0.y) * ac0.y
             + lrelu(v0.z + hr0.z) * ac0.z + lrelu(v0.w + hr0.w) * ac0.w
             + lrelu(v1.x + hr1.x) * ac1.x + lrelu(v1.y + hr1.y) * ac1.y
             + lrelu(v1.z + hr1.z) * ac1.z + lrelu(v1.w + hr1.w) * ac1.w;
    p0 += __shfl_xor(p0, 1); p1 += __shfl_xor(p1, 1);
    p0 += __shfl_xor(p0, 2); p1 += __shfl_xor(p1, 2);
    p0 += __shfl_xor(p0, 4); p1 += __shfl_xor(p1, 4);
    float w0 = __expf(p0), w1 = __expf(p1);
    den += w0 + w1;
    a0.x += w0 * u0.x + w1 * v0.x; a0.y += w0 * u0.y + w1 * v0.y;
    a0.z += w0 * u0.z + w1 * v0.z; a0.w += w0 * u0.w + w1 * v0.w;
    a1.x += w0 * u1.x + w1 * v1.x; a1.y += w0 * u1.y + w1 * v1.y;
    a1.z += w0 * u1.z + w1 * v1.z; a1.w += w0 * u1.w + w1 * v1.w;
  }
  for (; j < dg; ++j) {
    int s = esrc[rpn + j];
    const float4* hp = (const float4*)(hl2 + (size_t)s * 64 + l8 * 8);
    float4 u0 = hp[0], u1 = hp[1];
    float p = lrelu(u0.x + hr0.x) * ac0.x + lrelu(u0.y + hr0.y) * ac0.y
            + lrelu(u0.z + hr0.z) * ac0.z + lrelu(u0.w + hr0.w) * ac0.w
            + lrelu(u1.x + hr1.x) * ac1.x + lrelu(u1.y + hr1.y) * ac1.y
            + lrelu(u1.z + hr1.z) * ac1.z + lrelu(u1.w + hr1.w) * ac1.w;
    p += __shfl_xor(p, 1);
    p += __shfl_xor(p, 2);
    p += __shfl_xor(p, 4);
    float w = __expf(p);
    den += w;
    a0.x += w * u0.x; a0.y += w * u0.y; a0.z += w * u0.z; a0.w += w * u0.w;
    a1.x += w * u1.x; a1.y += w * u1.y; a1.z += w * u1.z; a1.w += w * u1.w;
  }
  float inv = 1.0f / (den + 1e-16f);
  float4 o0 = { a0.x * inv + bs0.x, a0.y * inv + bs0.y, a0.z * inv + bs0.z, a0.w * inv + bs0.w };
  float4 o1 = { a1.x * inv + bs1.x, a1.y * inv + bs1.y, a1.z * inv + bs1.z, a1.w * inv + bs1.w };
  float4* op = (float4*)(out2 + (size_t)n * 64 + l8 * 8);
  op[0] = o0; op[1] = o1;
}

// ======================= pooling: block partials (no global atomics) =======================
__global__ __launch_bounds__(256) void k_pool(
    const float* __restrict__ out2, const int* __restrict__ batch,
    float* __restrict__ ppart) {
  __shared__ float ssum[NG * 64];
  __shared__ float scnt[NG];
  int tid = threadIdx.x;
  for (int i = tid; i < NG * 64; i += 256) ssum[i] = 0.0f;
  if (tid < NG) scnt[tid] = 0.0f;
  __syncthreads();
  int total = NN * 64;
  for (int idx = blockIdx.x * 256 + tid; idx < total; idx += gridDim.x * 256) {
    int n = idx >> 6, c = idx & 63;
    int g = batch[n];
    atomicAdd(&ssum[g * 64 + c], out2[idx]);
    if (c == 0) atomicAdd(&scnt[g], 1.0f);
  }
  __syncthreads();
  float* pb = ppart + (size_t)blockIdx.x * (NG * 64 + NG);
  for (int i = tid; i < NG * 64; i += 256) pb[i] = ssum[i];
  if (tid < NG) pb[NG * 64 + tid] = scnt[tid];
}

__global__ __launch_bounds__(256) void k_final(
    const float* __restrict__ ppart, float* __restrict__ out) {
  int i = blockIdx.x * 256 + threadIdx.x;
  if (i >= NG * 64) return;
  int g = i >> 6;
  float s = 0.0f, c = 0.0f;
  for (int b = 0; b < NPB; ++b) {
    const float* pb = ppart + (size_t)b * (NG * 64 + NG);
    s += pb[i];
    c += pb[NG * 64 + g];
  }
  out[i] = s / fmaxf(c, 1.0f);
}

extern "C" void kernel_launch(void* const* d_in, const int* in_sizes, int n_in,
                              void* d_out, int out_size, void* d_ws, size_t ws_size,
                              hipStream_t stream) {
  const float* x     = (const float*)d_in[0];
  const int*   ei    = (const int*)d_in[1];
  const int*   batch = (const int*)d_in[2];
  const float* W1l   = (const float*)d_in[3];
  const float* b1l   = (const float*)d_in[4];
  const float* W1r   = (const float*)d_in[5];
  const float* b1r   = (const float*)d_in[6];
  const float* att1  = (const float*)d_in[7];
  const float* bias1 = (const float*)d_in[8];
  const float* W2l   = (const float*)d_in[9];
  const float* b2l   = (const float*)d_in[10];
  const float* W2r   = (const float*)d_in[11];
  const float* b2r   = (const float*)d_in[12];
  const float* att2  = (const float*)d_in[13];
  const float* bias2 = (const float*)d_in[14];
  float* ws = (float*)d_ws;
  int*   wi = (int*)d_ws;
  float* out = (float*)d_out;

  hipMemsetAsync(wi + OFF_DEG, 0, (size_t)NN * 4, stream);

  // CSR build (shared by both layers)
  k_count<<<2048, 256, 0, stream>>>(ei, wi + OFF_DEG);
  k_scan1<<<NBLK, 256, 0, stream>>>(wi + OFF_DEG, wi + OFF_TMP, wi + OFF_PART);
  k_scan2<<<1, 512, 0, stream>>>(wi + OFF_PART);
  k_scan3<<<NBLK, 256, 0, stream>>>(wi + OFF_DEG, wi + OFF_TMP, wi + OFF_PART,
                                    wi + OFF_RP, wi + OFF_CUR);
  k_scatter<<<2048, 256, 0, stream>>>(ei, wi + OFF_CUR, wi + OFF_ESRC);

  // layer 1
  k_xform1<<<NN / 16, 256, 0, stream>>>(x, W1l, b1l, W1r, b1r, ws + OFF_XL1, ws + OFF_XR1);
  k_gather1<<<NN / 8, 256, 0, stream>>>(wi + OFF_RP, wi + OFF_DEG, wi + OFF_ESRC,
                                        ws + OFF_XL1, ws + OFF_XR1, att1, bias1, ws + OFF_H);
  // layer 2
  k_xform2<<<NN / 8, 256, 0, stream>>>(ws + OFF_H, W2l, b2l, W2r, b2r,
                                       ws + OFF_HL2, ws + OFF_HR2);
  k_gather2<<<(NN * 8 + 255) / 256, 256, 0, stream>>>(wi + OFF_RP, wi + OFF_DEG, wi + OFF_ESRC,
                                                      ws + OFF_HL2, ws + OFF_HR2, att2, bias2,
                                                      ws + OFF_OUT2);
  k_pool<<<NPB, 256, 0, stream>>>(ws + OFF_OUT2, batch, ws + OFF_PPART);
  k_final<<<16, 256, 0, stream>>>(ws + OFF_PPART, out);
}

// Round 4
// 708.176 us; speedup vs baseline: 3.6798x; 1.2393x over previous
//
#include <hip/hip_runtime.h>
#include <math.h>

#define NN 100000
#define EE 3200000
#define ET (EE + NN)
#define NG 64
#define NPB 128        // pool partial blocks

// bucket sort params
#define NB 196         // ceil(NN/512) buckets
#define BWID 512       // nodes per bucket (dst >> 9)
#define BIN_S 24       // LDS staging entries per bucket
#define BIN_ROUNDS 2
#define BIN_CHUNK 4096 // edges per block (2 rounds x 2048)
#define BIN_BLOCKS 806 // ceil(ET/4096)

// workspace layout (4-byte units)
#define OFF_XL1   0u
#define OFF_XR1   3200000u
#define OFF_H     6400000u
#define OFF_HL2   9600000u
#define OFF_HR2   16000000u
#define OFF_OUT2  0u           /* reuses XL1/XR1 (dead after layer 1) */
#define OFF_BEDGE 9600000u     /* int2[ET] aliases HL2/HR2 (dead until xform2) */
#define OFF_PPART 22400000u    /* NPB * 4160 */
#define OFF_RP    22932480u    /* NN+1 */
#define OFF_ESRC  23032488u    /* ET */
#define OFF_BCNT  26332488u
#define OFF_BOFF  26332688u
#define OFF_GCUR  26332888u
#define WS_UNITS  26333088u

__device__ __forceinline__ float lrelu(float v) { return v > 0.0f ? v : 0.2f * v; }

// ======================= bucket counting sort: CSR build =======================
__global__ __launch_bounds__(256) void k_bcount(const int* __restrict__ ei,
                                                int* __restrict__ bcnt) {
  __shared__ int h[NB];
  for (int i = threadIdx.x; i < NB; i += 256) h[i] = 0;
  __syncthreads();
  for (long e = (long)blockIdx.x * 256 + threadIdx.x; e < ET; e += (long)gridDim.x * 256) {
    int d = (e < EE) ? ei[EE + e] : (int)(e - EE);
    atomicAdd(&h[d >> 9], 1);
  }
  __syncthreads();
  for (int i = threadIdx.x; i < NB; i += 256) if (h[i]) atomicAdd(&bcnt[i], h[i]);
}

__global__ __launch_bounds__(256) void k_bscan(const int* __restrict__ bcnt,
                                               int* __restrict__ boff, int* __restrict__ gcur) {
  __shared__ int sd[256];
  int t = threadIdx.x;
  int v = (t < NB) ? bcnt[t] : 0;
  sd[t] = v;
  __syncthreads();
  for (int o = 1; o < 256; o <<= 1) {
    int u = (t >= o) ? sd[t - o] : 0;
    __syncthreads();
    sd[t] += u;
    __syncthreads();
  }
  if (t < NB) { boff[t] = sd[t] - v; gcur[t] = sd[t] - v; }
  if (t == 0) boff[NB] = ET;
}

// LDS-staged binning: edges -> bucket-contiguous bedge[] (dense writes)
__global__ __launch_bounds__(256) void k_bin(const int* __restrict__ ei,
                                             int* __restrict__ gcur, int2* __restrict__ bedge) {
  __shared__ int cnt[NB];
  __shared__ int2 stage[NB][BIN_S];
  int tid = threadIdx.x;
  for (int i = tid; i < NB; i += 256) cnt[i] = 0;
  __syncthreads();
  long base = (long)blockIdx.x * BIN_CHUNK;
  for (int r = 0; r < BIN_ROUNDS; ++r) {
#pragma unroll
    for (int k = 0; k < 8; ++k) {
      long e = base + r * 2048 + k * 256 + tid;
      if (e < ET) {
        int s, d;
        if (e < EE) { s = ei[e]; d = ei[EE + e]; }
        else { s = (int)(e - EE); d = s; }
        int b = d >> 9;
        int k2 = atomicAdd(&cnt[b], 1);
        if (k2 < BIN_S) stage[b][k2] = make_int2(s, d);
        else { int p = atomicAdd(&gcur[b], 1); bedge[p] = make_int2(s, d); }
      }
    }
    __syncthreads();
    for (int b = tid; b < NB; b += 256) {
      int c = cnt[b] < BIN_S ? cnt[b] : BIN_S;
      if (c > 0) {
        int p = atomicAdd(&gcur[b], c);
        for (int j = 0; j < c; ++j) bedge[p + j] = stage[b][j];
        cnt[b] = 0;
      }
    }
    __syncthreads();
  }
}

// per-bucket: LDS node-degree count + scan -> rp; LDS cursors -> esrc (dense)
__global__ __launch_bounds__(512) void k_csr(const int* __restrict__ boff,
                                             const int2* __restrict__ bedge,
                                             int* __restrict__ rp, int* __restrict__ esrc) {
  __shared__ int sdeg[BWID];
  __shared__ int sscan[BWID];
  int b = blockIdx.x, t = threadIdx.x;
  int n0 = b * BWID;
  int lo = boff[b], hi = boff[b + 1];
  sdeg[t] = 0;
  __syncthreads();
  for (int i = lo + t; i < hi; i += 512) {
    int2 ed = bedge[i];
    atomicAdd(&sdeg[ed.y - n0], 1);
  }
  __syncthreads();
  int v = sdeg[t];
  sscan[t] = v;
  __syncthreads();
  for (int o = 1; o < 512; o <<= 1) {
    int u = (t >= o) ? sscan[t - o] : 0;
    __syncthreads();
    sscan[t] += u;
    __syncthreads();
  }
  int excl = sscan[t] - v;
  int n = n0 + t;
  if (n < NN) rp[n] = lo + excl;
  if (b == NB - 1 && t == 0) rp[NN] = ET;
  __syncthreads();
  sdeg[t] = lo + excl;   // reuse as cursor
  __syncthreads();
  for (int i = lo + t; i < hi; i += 512) {
    int2 ed = bedge[i];
    int p = atomicAdd(&sdeg[ed.y - n0], 1);
    esrc[p] = ed.x;
  }
}

// ======================= layer-1 transform =======================
__global__ __launch_bounds__(256) void k_xform1(
    const float* __restrict__ x,
    const float* __restrict__ Wl, const float* __restrict__ bl,
    const float* __restrict__ Wr, const float* __restrict__ br,
    float* __restrict__ xl1, float* __restrict__ xr1) {
  __shared__ float Wlds[256 * 64];
  int tid = threadIdx.x;
  for (int i = tid; i < 256 * 64; i += 256) {
    int k = i >> 6, c = i & 63;
    Wlds[i] = (c < 32) ? Wl[k * 32 + c] : Wr[k * 32 + (c - 32)];
  }
  __syncthreads();
  int n = blockIdx.x * 16 + (tid >> 4);
  int cbase = (tid & 15) * 4;
  const float4* xrow = (const float4*)(x + (size_t)n * 256);
  float a0 = 0.f, a1 = 0.f, a2 = 0.f, a3 = 0.f;
#pragma unroll 4
  for (int k = 0; k < 256; k += 4) {
    float4 xv = xrow[k >> 2];
    const float* wr = &Wlds[k * 64 + cbase];
    float4 w0 = *(const float4*)(wr);
    float4 w1 = *(const float4*)(wr + 64);
    float4 w2 = *(const float4*)(wr + 128);
    float4 w3 = *(const float4*)(wr + 192);
    a0 += xv.x * w0.x + xv.y * w1.x + xv.z * w2.x + xv.w * w3.x;
    a1 += xv.x * w0.y + xv.y * w1.y + xv.z * w2.y + xv.w * w3.y;
    a2 += xv.x * w0.z + xv.y * w1.z + xv.z * w2.z + xv.w * w3.z;
    a3 += xv.x * w0.w + xv.y * w1.w + xv.z * w2.w + xv.w * w3.w;
  }
  if (cbase < 32) {
    float4 o = { a0 + bl[cbase], a1 + bl[cbase + 1], a2 + bl[cbase + 2], a3 + bl[cbase + 3] };
    *(float4*)(xl1 + (size_t)n * 32 + cbase) = o;
  } else {
    int c2 = cbase - 32;
    float4 o = { a0 + br[c2], a1 + br[c2 + 1], a2 + br[c2 + 2], a3 + br[c2 + 3] };
    *(float4*)(xr1 + (size_t)n * 32 + c2) = o;
  }
}

// ======================= layer-1 gather, unroll x4 =======================
__global__ __launch_bounds__(256) void k_gather1(
    const int* __restrict__ rp, const int* __restrict__ esrc,
    const float* __restrict__ xl1, const float* __restrict__ xr1,
    const float* __restrict__ att1, const float* __restrict__ bias1,
    float* __restrict__ h) {
  int n = blockIdx.x * 8 + (threadIdx.x >> 5);
  if (n >= NN) return;
  int l = threadIdx.x & 31;
  float av = att1[l];
  float xr = xr1[(size_t)n * 32 + l];
  int rpn = rp[n], dg = rp[n + 1] - rpn;
  float acc = 0.0f, den = 0.0f;
  int j = 0;
  for (; j + 4 <= dg; j += 4) {
    int s0 = esrc[rpn + j + 0];
    int s1 = esrc[rpn + j + 1];
    int s2 = esrc[rpn + j + 2];
    int s3 = esrc[rpn + j + 3];
    float x0 = xl1[(size_t)s0 * 32 + l];
    float x1 = xl1[(size_t)s1 * 32 + l];
    float x2 = xl1[(size_t)s2 * 32 + l];
    float x3 = xl1[(size_t)s3 * 32 + l];
    float p0 = lrelu(x0 + xr) * av;
    float p1 = lrelu(x1 + xr) * av;
    float p2 = lrelu(x2 + xr) * av;
    float p3 = lrelu(x3 + xr) * av;
    p0 += __shfl_xor(p0, 1); p1 += __shfl_xor(p1, 1);
    p2 += __shfl_xor(p2, 1); p3 += __shfl_xor(p3, 1);
    p0 += __shfl_xor(p0, 2); p1 += __shfl_xor(p1, 2);
    p2 += __shfl_xor(p2, 2); p3 += __shfl_xor(p3, 2);
    float w0 = __expf(p0), w1 = __expf(p1), w2 = __expf(p2), w3 = __expf(p3);
    den += w0 + w1 + w2 + w3;
    acc += w0 * x0 + w1 * x1 + w2 * x2 + w3 * x3;
  }
  for (; j < dg; ++j) {
    int s = esrc[rpn + j];
    float xl = xl1[(size_t)s * 32 + l];
    float p = lrelu(xl + xr) * av;
    p += __shfl_xor(p, 1);
    p += __shfl_xor(p, 2);
    float w = __expf(p);
    den += w;
    acc += w * xl;
  }
  float v = acc / (den + 1e-16f) + bias1[l];
  h[(size_t)n * 32 + l] = v > 0.0f ? v : expm1f(v);
}

// ======================= layer-2 transform =======================
__global__ __launch_bounds__(256) void k_xform2(
    const float* __restrict__ h,
    const float* __restrict__ Wl, const float* __restrict__ bl,
    const float* __restrict__ Wr, const float* __restrict__ br,
    float* __restrict__ hl2, float* __restrict__ hr2) {
  __shared__ float Wlds[32 * 128];
  int tid = threadIdx.x;
  for (int i = tid; i < 32 * 128; i += 256) {
    int k = i >> 7, c = i & 127;
    Wlds[i] = (c < 64) ? Wl[k * 64 + c] : Wr[k * 64 + (c - 64)];
  }
  __syncthreads();
  int n = blockIdx.x * 8 + (tid >> 5);
  int cbase = (tid & 31) * 4;
  const float4* hrow = (const float4*)(h + (size_t)n * 32);
  float a0 = 0.f, a1 = 0.f, a2 = 0.f, a3 = 0.f;
#pragma unroll
  for (int k = 0; k < 32; k += 4) {
    float4 xv = hrow[k >> 2];
    const float* wr = &Wlds[k * 128 + cbase];
    float4 w0 = *(const float4*)(wr);
    float4 w1 = *(const float4*)(wr + 128);
    float4 w2 = *(const float4*)(wr + 256);
    float4 w3 = *(const float4*)(wr + 384);
    a0 += xv.x * w0.x + xv.y * w1.x + xv.z * w2.x + xv.w * w3.x;
    a1 += xv.x * w0.y + xv.y * w1.y + xv.z * w2.y + xv.w * w3.y;
    a2 += xv.x * w0.z + xv.y * w1.z + xv.z * w2.z + xv.w * w3.z;
    a3 += xv.x * w0.w + xv.y * w1.w + xv.z * w2.w + xv.w * w3.w;
  }
  if (cbase < 64) {
    float4 o = { a0 + bl[cbase], a1 + bl[cbase + 1], a2 + bl[cbase + 2], a3 + bl[cbase + 3] };
    *(float4*)(hl2 + (size_t)n * 64 + cbase) = o;
  } else {
    int c2 = cbase - 64;
    float4 o = { a0 + br[c2], a1 + br[c2 + 1], a2 + br[c2 + 2], a3 + br[c2 + 3] };
    *(float4*)(hr2 + (size_t)n * 64 + c2) = o;
  }
}

// ======================= layer-2 gather (dense out), unroll x2 =======================
__global__ __launch_bounds__(256) void k_gather2(
    const int* __restrict__ rp, const int* __restrict__ esrc,
    const float* __restrict__ hl2, const float* __restrict__ hr2,
    const float* __restrict__ att2, const float* __restrict__ bias2,
    float* __restrict__ out2) {
  int n = (blockIdx.x * 256 + threadIdx.x) >> 3;
  if (n >= NN) return;
  int l8 = threadIdx.x & 7;
  float4 ac0 = *(const float4*)(att2 + l8 * 8);
  float4 ac1 = *(const float4*)(att2 + l8 * 8 + 4);
  float4 bs0 = *(const float4*)(bias2 + l8 * 8);
  float4 bs1 = *(const float4*)(bias2 + l8 * 8 + 4);
  const float4* hrp = (const float4*)(hr2 + (size_t)n * 64 + l8 * 8);
  float4 hr0 = hrp[0], hr1 = hrp[1];
  int rpn = rp[n], dg = rp[n + 1] - rpn;
  float4 a0 = {0,0,0,0}, a1 = {0,0,0,0};
  float den = 0.0f;
  int j = 0;
  for (; j + 2 <= dg; j += 2) {
    int s0 = esrc[rpn + j];
    int s1 = esrc[rpn + j + 1];
    const float4* hp0 = (const float4*)(hl2 + (size_t)s0 * 64 + l8 * 8);
    const float4* hp1 = (const float4*)(hl2 + (size_t)s1 * 64 + l8 * 8);
    float4 u0 = hp0[0], u1 = hp0[1];
    float4 v0 = hp1[0], v1 = hp1[1];
    float p0 = lrelu(u0.x + hr0.x) * ac0.x + lrelu(u0.y + hr0.y) * ac0.y
             + lrelu(u0.z + hr0.z) * ac0.z + lrelu(u0.w + hr0.w) * ac0.w
             + lrelu(u1.x + hr1.x) * ac1.x + lrelu(u1.y + hr1.y) * ac1.y
             + lrelu(u1.z + hr1.z) * ac1.z + lrelu(u1.w + hr1.w) * ac1.w;
    float p1 = lrelu(v0.x + hr0.x) * ac0.x + lrelu(v0.y + hr0.y) * ac0.y
             + lrelu(v0.z + hr0.z) * ac0.z + lrelu(v0.w + hr0.w) * ac0.w
             + lrelu(v1.x + hr1.x) * ac1.x + lrelu(v1.y + hr1.y) * ac1.y
             + lrelu(v1.z + hr1.z) * ac1.z + lrelu(v1.w + hr1.w) * ac1.w;
    p0 += __shfl_xor(p0, 1); p1 += __shfl_xor(p1, 1);
    p0 += __shfl_xor(p0, 2); p1 += __shfl_xor(p1, 2);
    p0 += __shfl_xor(p0, 4); p1 += __shfl_xor(p1, 4);
    float w0 = __expf(p0), w1 = __expf(p1);
    den += w0 + w1;
    a0.x += w0 * u0.x + w1 * v0.x; a0.y += w0 * u0.y + w1 * v0.y;
    a0.z += w0 * u0.z + w1 * v0.z; a0.w += w0 * u0.w + w1 * v0.w;
    a1.x += w0 * u1.x + w1 * v1.x; a1.y += w0 * u1.y + w1 * v1.y;
    a1.z += w0 * u1.z + w1 * v1.z; a1.w += w0 * u1.w + w1 * v1.w;
  }
  for (; j < dg; ++j) {
    int s = esrc[rpn + j];
    const float4* hp = (const float4*)(hl2 + (size_t)s * 64 + l8 * 8);
    float4 u0 = hp[0], u1 = hp[1];
    float p = lrelu(u0.x + hr0.x) * ac0.x + lrelu(u0.y + hr0.y) * ac0.y
            + lrelu(u0.z + hr0.z) * ac0.z + lrelu(u0.w + hr0.w) * ac0.w
            + lrelu(u1.x + hr1.x) * ac1.x + lrelu(u1.y + hr1.y) * ac1.y
            + lrelu(u1.z + hr1.z) * ac1.z + lrelu(u1.w + hr1.w) * ac1.w;
    p += __shfl_xor(p, 1);
    p += __shfl_xor(p, 2);
    p += __shfl_xor(p, 4);
    float w = __expf(p);
    den += w;
    a0.x += w * u0.x; a0.y += w * u0.y; a0.z += w * u0.z; a0.w += w * u0.w;
    a1.x += w * u1.x; a1.y += w * u1.y; a1.z += w * u1.z; a1.w += w * u1.w;
  }
  float inv = 1.0f / (den + 1e-16f);
  float4 o0 = { a0.x * inv + bs0.x, a0.y * inv + bs0.y, a0.z * inv + bs0.z, a0.w * inv + bs0.w };
  float4 o1 = { a1.x * inv + bs1.x, a1.y * inv + bs1.y, a1.z * inv + bs1.z, a1.w * inv + bs1.w };
  float4* op = (float4*)(out2 + (size_t)n * 64 + l8 * 8);
  op[0] = o0; op[1] = o1;
}

// ======================= pooling =======================
__global__ __launch_bounds__(256) void k_pool(
    const float* __restrict__ out2, const int* __restrict__ batch,
    float* __restrict__ ppart) {
  __shared__ float ssum[NG * 64];
  __shared__ float scnt[NG];
  int tid = threadIdx.x;
  for (int i = tid; i < NG * 64; i += 256) ssum[i] = 0.0f;
  if (tid < NG) scnt[tid] = 0.0f;
  __syncthreads();
  int total = NN * 64;
  for (int idx = blockIdx.x * 256 + tid; idx < total; idx += gridDim.x * 256) {
    int n = idx >> 6, c = idx & 63;
    int g = batch[n];
    atomicAdd(&ssum[g * 64 + c], out2[idx]);
    if (c == 0) atomicAdd(&scnt[g], 1.0f);
  }
  __syncthreads();
  float* pb = ppart + (size_t)blockIdx.x * (NG * 64 + NG);
  for (int i = tid; i < NG * 64; i += 256) pb[i] = ssum[i];
  if (tid < NG) pb[NG * 64 + tid] = scnt[tid];
}

__global__ __launch_bounds__(256) void k_final(
    const float* __restrict__ ppart, float* __restrict__ out) {
  int i = blockIdx.x * 256 + threadIdx.x;
  if (i >= NG * 64) return;
  int g = i >> 6;
  float s = 0.0f, c = 0.0f;
  for (int b = 0; b < NPB; ++b) {
    const float* pb = ppart + (size_t)b * (NG * 64 + NG);
    s += pb[i];
    c += pb[NG * 64 + g];
  }
  out[i] = s / fmaxf(c, 1.0f);
}

extern "C" void kernel_launch(void* const* d_in, const int* in_sizes, int n_in,
                              void* d_out, int out_size, void* d_ws, size_t ws_size,
                              hipStream_t stream) {
  const float* x     = (const float*)d_in[0];
  const int*   ei    = (const int*)d_in[1];
  const int*   batch = (const int*)d_in[2];
  const float* W1l   = (const float*)d_in[3];
  const float* b1l   = (const float*)d_in[4];
  const float* W1r   = (const float*)d_in[5];
  const float* b1r   = (const float*)d_in[6];
  const float* att1  = (const float*)d_in[7];
  const float* bias1 = (const float*)d_in[8];
  const float* W2l   = (const float*)d_in[9];
  const float* b2l   = (const float*)d_in[10];
  const float* W2r   = (const float*)d_in[11];
  const float* b2r   = (const float*)d_in[12];
  const float* att2  = (const float*)d_in[13];
  const float* bias2 = (const float*)d_in[14];
  float* ws = (float*)d_ws;
  int*   wi = (int*)d_ws;
  float* out = (float*)d_out;

  hipMemsetAsync(wi + OFF_BCNT, 0, NB * 4, stream);

  // CSR build via bucket counting sort
  k_bcount<<<512, 256, 0, stream>>>(ei, wi + OFF_BCNT);
  k_bscan<<<1, 256, 0, stream>>>(wi + OFF_BCNT, wi + OFF_BOFF, wi + OFF_GCUR);
  k_bin<<<BIN_BLOCKS, 256, 0, stream>>>(ei, wi + OFF_GCUR, (int2*)(wi + OFF_BEDGE));
  k_csr<<<NB, 512, 0, stream>>>(wi + OFF_BOFF, (const int2*)(wi + OFF_BEDGE),
                                wi + OFF_RP, wi + OFF_ESRC);

  // layer 1
  k_xform1<<<NN / 16, 256, 0, stream>>>(x, W1l, b1l, W1r, b1r, ws + OFF_XL1, ws + OFF_XR1);
  k_gather1<<<NN / 8, 256, 0, stream>>>(wi + OFF_RP, wi + OFF_ESRC,
                                        ws + OFF_XL1, ws + OFF_XR1, att1, bias1, ws + OFF_H);
  // layer 2 (xform2 overwrites bedge region — bedge is dead by then)
  k_xform2<<<NN / 8, 256, 0, stream>>>(ws + OFF_H, W2l, b2l, W2r, b2r,
                                       ws + OFF_HL2, ws + OFF_HR2);
  k_gather2<<<(NN * 8 + 255) / 256, 256, 0, stream>>>(wi + OFF_RP, wi + OFF_ESRC,
                                                      ws + OFF_HL2, ws + OFF_HR2, att2, bias2,
                                                      ws + OFF_OUT2);
  k_pool<<<NPB, 256, 0, stream>>>(ws + OFF_OUT2, batch, ws + OFF_PPART);
  k_final<<<16, 256, 0, stream>>>(ws + OFF_PPART, out);
}